// Round 5
// baseline (338.775 us; speedup 1.0000x reference)
//
#include <hip/hip_runtime.h>
#include <math.h>

#define N_NODES 65536
#define N_EDGES 1048576
#define HDIM 64
#define NCLS 10
#define NGRAPH 256
#define NLAYER 3
#define BN_EPS 1e-5f

// ---------------- degree count ----------------

__global__ __launch_bounds__(256) void deg_count_kernel(const int* __restrict__ dst,
                                                        unsigned* __restrict__ cnt) {
    int e = blockIdx.x * 256 + threadIdx.x;
    if (e < N_EDGES) atomicAdd(&cnt[dst[e]], 1u);
}

// ---------------- CSR build: exclusive scan (+ dis fused) ----------------

__global__ __launch_bounds__(256) void scan1_kernel(const unsigned* __restrict__ cnt,
                                                    unsigned* __restrict__ offsets,
                                                    unsigned* __restrict__ bsum,
                                                    float* __restrict__ dis) {
    __shared__ unsigned lds[256];
    int t = threadIdx.x, b = blockIdx.x;
    unsigned v = cnt[b * 256 + t];
    dis[b * 256 + t] = rsqrtf((float)(v + 1u));
    lds[t] = v;
    __syncthreads();
#pragma unroll
    for (int off = 1; off < 256; off <<= 1) {
        unsigned add = (t >= off) ? lds[t - off] : 0u;
        __syncthreads();
        lds[t] += add;
        __syncthreads();
    }
    offsets[b * 256 + t] = lds[t] - v;  // exclusive within block
    if (t == 255) bsum[b] = lds[255];
}

__global__ __launch_bounds__(256) void scan2_kernel(unsigned* __restrict__ bsum,
                                                    unsigned* __restrict__ carry,
                                                    unsigned* __restrict__ offsets) {
    __shared__ unsigned lds[256];
    int t = threadIdx.x;
    unsigned v = bsum[t];
    lds[t] = v;
    __syncthreads();
#pragma unroll
    for (int off = 1; off < 256; off <<= 1) {
        unsigned add = (t >= off) ? lds[t - off] : 0u;
        __syncthreads();
        lds[t] += add;
        __syncthreads();
    }
    carry[t] = lds[t] - v;  // exclusive
    if (t == 255) offsets[N_NODES] = lds[255];  // total = E
}

// also seeds cursor with the final offsets so fill's atomicAdd returns the slot directly
__global__ __launch_bounds__(256) void scan3_kernel(unsigned* __restrict__ offsets,
                                                    const unsigned* __restrict__ carry,
                                                    unsigned* __restrict__ cursor) {
    int i = blockIdx.x * 256 + threadIdx.x;
    if (i < N_NODES) {
        unsigned o = offsets[i] + carry[i >> 8];
        offsets[i] = o;
        cursor[i] = o;
    }
}

__global__ __launch_bounds__(256) void fill_kernel(const int* __restrict__ ei,
                                                   const float* __restrict__ dis,
                                                   unsigned* __restrict__ cursor,
                                                   int2* __restrict__ edat) {
    int e = blockIdx.x * 256 + threadIdx.x;
    if (e < N_EDGES) {
        int s = ei[e];
        int d = ei[N_EDGES + e];
        unsigned pos = atomicAdd(&cursor[d], 1u);
        float c = dis[s] * dis[d];
        edat[pos] = make_int2(s, __float_as_int(c));
    }
}

// ---------------- pull aggregate: t[n] = dis[n]^2*h[n] + sum coef*h[src] ----------------
// one wave per node; lanes = 4 edge-slots x 16 float4-feature lanes.
// main loop: 16 edges (gathers) in flight per wave.

__global__ __launch_bounds__(256) void aggregate_kernel(const float* __restrict__ hin,
                                                        const float* __restrict__ dis,
                                                        const unsigned* __restrict__ offsets,
                                                        const int2* __restrict__ edat,
                                                        float* __restrict__ t) {
    int n = (blockIdx.x * 256 + threadIdx.x) >> 6;
    int lane = threadIdx.x & 63;
    int eslot = lane >> 4;      // 0..3
    int fq = lane & 15;         // float4 feature index
    int e0 = (int)offsets[n];
    int e1 = (int)offsets[n + 1];

    float4 acc = make_float4(0.f, 0.f, 0.f, 0.f);
    int e = e0 + eslot;
    // unrolled x4: 16 edges in flight across the wave
    for (; e + 12 < e1; e += 16) {
        int2 s0 = edat[e];
        int2 s1 = edat[e + 4];
        int2 s2 = edat[e + 8];
        int2 s3 = edat[e + 12];
        float c0 = __int_as_float(s0.y);
        float c1 = __int_as_float(s1.y);
        float c2 = __int_as_float(s2.y);
        float c3 = __int_as_float(s3.y);
        float4 v0 = *(const float4*)&hin[(size_t)s0.x * HDIM + (fq << 2)];
        float4 v1 = *(const float4*)&hin[(size_t)s1.x * HDIM + (fq << 2)];
        float4 v2 = *(const float4*)&hin[(size_t)s2.x * HDIM + (fq << 2)];
        float4 v3 = *(const float4*)&hin[(size_t)s3.x * HDIM + (fq << 2)];
        acc.x += v0.x * c0; acc.y += v0.y * c0; acc.z += v0.z * c0; acc.w += v0.w * c0;
        acc.x += v1.x * c1; acc.y += v1.y * c1; acc.z += v1.z * c1; acc.w += v1.w * c1;
        acc.x += v2.x * c2; acc.y += v2.y * c2; acc.z += v2.z * c2; acc.w += v2.w * c2;
        acc.x += v3.x * c3; acc.y += v3.y * c3; acc.z += v3.z * c3; acc.w += v3.w * c3;
    }
    for (; e < e1; e += 4) {
        int2 sa = edat[e];
        float ca = __int_as_float(sa.y);
        float4 va = *(const float4*)&hin[(size_t)sa.x * HDIM + (fq << 2)];
        acc.x += va.x * ca; acc.y += va.y * ca; acc.z += va.z * ca; acc.w += va.w * ca;
    }
    // reduce across edge slots (lanes l, l^16, l^32, l^48)
    acc.x += __shfl_xor(acc.x, 16); acc.y += __shfl_xor(acc.y, 16);
    acc.z += __shfl_xor(acc.z, 16); acc.w += __shfl_xor(acc.w, 16);
    acc.x += __shfl_xor(acc.x, 32); acc.y += __shfl_xor(acc.y, 32);
    acc.z += __shfl_xor(acc.z, 32); acc.w += __shfl_xor(acc.w, 32);
    if (eslot == 0) {
        float d = dis[n];
        float d2 = d * d;
        float4 sv = *(const float4*)&hin[(size_t)n * HDIM + (fq << 2)];
        acc.x += sv.x * d2; acc.y += sv.y * d2;
        acc.z += sv.z * d2; acc.w += sv.w * d2;
        *(float4*)&t[(size_t)n * HDIM + (fq << 2)] = acc;
    }
}

// ---------------- GEMM t@W fused with bias+BN+ReLU+residual ----------------

__global__ __launch_bounds__(256) void gemm_kernel(const float* __restrict__ tin,
                                                   const float* __restrict__ W,
                                                   const float* __restrict__ bias,
                                                   const float* __restrict__ gamma,
                                                   const float* __restrict__ beta,
                                                   const float* __restrict__ mean,
                                                   const float* __restrict__ var,
                                                   float* __restrict__ h,
                                                   int has_res) {
    __shared__ float hs[64][68];
    __shared__ float ws[64 * 64];
    int tid = threadIdx.x;
    int row0 = blockIdx.x * 64;

    {
        const float4* Wv = (const float4*)W;
        float4* wsv = (float4*)ws;
#pragma unroll
        for (int i = 0; i < 4; ++i) wsv[tid + i * 256] = Wv[tid + i * 256];
    }
    {
        const float4* Hv = (const float4*)(tin + (size_t)row0 * HDIM);
#pragma unroll
        for (int i = 0; i < 4; ++i) {
            int idx = tid + i * 256;
            int r = idx >> 4;
            int c = (idx & 15) << 2;
            *(float4*)&hs[r][c] = Hv[idx];
        }
    }
    __syncthreads();

    int tx = tid & 15, ty = tid >> 4;
    float acc[4][4] = {};
#pragma unroll
    for (int kq = 0; kq < 16; ++kq) {
        int k = kq * 4;
        float4 a[4], b[4];
#pragma unroll
        for (int i = 0; i < 4; ++i) a[i] = *(const float4*)&hs[ty * 4 + i][k];
#pragma unroll
        for (int kk = 0; kk < 4; ++kk) b[kk] = *(const float4*)&ws[(k + kk) * 64 + tx * 4];
#pragma unroll
        for (int kk = 0; kk < 4; ++kk) {
            float b0 = b[kk].x, b1 = b[kk].y, b2 = b[kk].z, b3 = b[kk].w;
#pragma unroll
            for (int i = 0; i < 4; ++i) {
                float av = (kk == 0) ? a[i].x : (kk == 1) ? a[i].y : (kk == 2) ? a[i].z : a[i].w;
                acc[i][0] += av * b0;
                acc[i][1] += av * b1;
                acc[i][2] += av * b2;
                acc[i][3] += av * b3;
            }
        }
    }

    float4 b4 = ((const float4*)bias)[tx];
    float4 g4 = ((const float4*)gamma)[tx];
    float4 be4 = ((const float4*)beta)[tx];
    float4 m4 = ((const float4*)mean)[tx];
    float4 va4 = ((const float4*)var)[tx];
    float sc0 = g4.x * rsqrtf(va4.x + BN_EPS);
    float sc1 = g4.y * rsqrtf(va4.y + BN_EPS);
    float sc2 = g4.z * rsqrtf(va4.z + BN_EPS);
    float sc3 = g4.w * rsqrtf(va4.w + BN_EPS);
    float sh0 = (b4.x - m4.x) * sc0 + be4.x;
    float sh1 = (b4.y - m4.y) * sc1 + be4.y;
    float sh2 = (b4.z - m4.z) * sc2 + be4.z;
    float sh3 = (b4.w - m4.w) * sc3 + be4.w;

#pragma unroll
    for (int i = 0; i < 4; ++i) {
        int row = row0 + ty * 4 + i;
        float o0 = fmaxf(acc[i][0] * sc0 + sh0, 0.0f);
        float o1 = fmaxf(acc[i][1] * sc1 + sh1, 0.0f);
        float o2 = fmaxf(acc[i][2] * sc2 + sh2, 0.0f);
        float o3 = fmaxf(acc[i][3] * sc3 + sh3, 0.0f);
        if (has_res) {
            float4 r = *(const float4*)&h[(size_t)row * HDIM + tx * 4];
            o0 += r.x; o1 += r.y; o2 += r.z; o3 += r.w;
        }
        *(float4*)&h[(size_t)row * HDIM + tx * 4] = make_float4(o0, o1, o2, o3);
    }
}

// ---------------- global mean pool over sorted batch ----------------

__device__ __forceinline__ int lower_bound_batch(const int* __restrict__ batch, int val) {
    int lo = 0, hi = N_NODES;
    while (lo < hi) {
        int mid = (lo + hi) >> 1;
        if (batch[mid] < val) lo = mid + 1; else hi = mid;
    }
    return lo;
}

__global__ __launch_bounds__(256) void pool_kernel(const float* __restrict__ h,
                                                   const int* __restrict__ batch,
                                                   float* __restrict__ repr) {
    int g = blockIdx.x;
    int start = lower_bound_batch(batch, g);
    int end = lower_bound_batch(batch, g + 1);
    int f = threadIdx.x & 63;
    int grp = threadIdx.x >> 6;
    float s = 0.0f;
    for (int n = start + grp; n < end; n += 4) s += h[(size_t)n * HDIM + f];
    __shared__ float red[4][64];
    red[grp][f] = s;
    __syncthreads();
    if (grp == 0) {
        float tot = red[0][f] + red[1][f] + red[2][f] + red[3][f];
        int cnt = end - start;
        repr[g * HDIM + f] = tot / (float)(cnt > 0 ? cnt : 1);
    }
}

// ---------------- classifier ----------------

__global__ __launch_bounds__(64) void classify_kernel(const float* __restrict__ repr,
                                                      const float* __restrict__ w1,
                                                      const float* __restrict__ b1,
                                                      const float* __restrict__ w2,
                                                      const float* __restrict__ b2,
                                                      float* __restrict__ out) {
    int g = blockIdx.x;
    int j = threadIdx.x;
    __shared__ float r[64], z[64], lg[NCLS];
    r[j] = repr[g * HDIM + j];
    __syncthreads();
    float acc = b1[j];
#pragma unroll 8
    for (int k = 0; k < HDIM; ++k) acc += r[k] * w1[k * HDIM + j];
    z[j] = fmaxf(acc, 0.0f);
    __syncthreads();
    if (j < NCLS) {
        float a2 = b2[j];
#pragma unroll 8
        for (int k = 0; k < HDIM; ++k) a2 += z[k] * w2[k * NCLS + j];
        lg[j] = a2;
    }
    __syncthreads();
    if (j < NCLS) {
        float m = -1e30f;
#pragma unroll
        for (int c = 0; c < NCLS; ++c) m = fmaxf(m, lg[c]);
        float s = 0.0f;
#pragma unroll
        for (int c = 0; c < NCLS; ++c) s += expf(lg[c] - m);
        out[g * NCLS + j] = lg[j] - m - logf(s);
    }
}

// ---------------- host side ----------------

extern "C" void kernel_launch(void* const* d_in, const int* in_sizes, int n_in,
                              void* d_out, int out_size, void* d_ws, size_t ws_size,
                              hipStream_t stream) {
    const float* x        = (const float*)d_in[0];
    const float* conv_w   = (const float*)d_in[1];
    const float* conv_b   = (const float*)d_in[2];
    const float* bn_gamma = (const float*)d_in[3];
    const float* bn_beta  = (const float*)d_in[4];
    const float* bn_mean  = (const float*)d_in[5];
    const float* bn_var   = (const float*)d_in[6];
    const float* cls_w1   = (const float*)d_in[7];
    const float* cls_b1   = (const float*)d_in[8];
    const float* cls_w2   = (const float*)d_in[9];
    const float* cls_b2   = (const float*)d_in[10];
    const int* edge_index = (const int*)d_in[11];
    const int* batch      = (const int*)d_in[12];
    float* out = (float*)d_out;

    char* ws = (char*)d_ws;
    unsigned* cnt     = (unsigned*)(ws);                  // 256 KiB
    float*    dis     = (float*)(ws + (256u << 10));      // 256 KiB
    unsigned* offsets = (unsigned*)(ws + (512u << 10));   // 256 KiB + 4
    unsigned* bsum    = (unsigned*)(ws + (832u << 10));   // 1 KiB
    unsigned* carry   = (unsigned*)(ws + (833u << 10));   // 1 KiB
    unsigned* cursor  = (unsigned*)(ws + (840u << 10));   // 256 KiB
    int2*     edat    = (int2*)(ws + (2u << 20));         // 8 MiB (src, coef packed)
    float*    t       = (float*)(ws + (10u << 20));       // 16 MiB
    float*    h       = (float*)(ws + (26u << 20));       // 16 MiB
    float*    repr    = (float*)(ws + (42u << 20));       // 64 KiB

    // ---- preprocessing (CSR by dst) ----
    hipMemsetAsync(cnt, 0, N_NODES * sizeof(unsigned), stream);
    deg_count_kernel<<<N_EDGES / 256, 256, 0, stream>>>(edge_index + N_EDGES, cnt);
    scan1_kernel<<<N_NODES / 256, 256, 0, stream>>>(cnt, offsets, bsum, dis);
    scan2_kernel<<<1, 256, 0, stream>>>(bsum, carry, offsets);
    scan3_kernel<<<N_NODES / 256, 256, 0, stream>>>(offsets, carry, cursor);
    fill_kernel<<<N_EDGES / 256, 256, 0, stream>>>(edge_index, dis, cursor, edat);

    // ---- layers ----
    for (int l = 0; l < NLAYER; ++l) {
        const float* hin = (l == 0) ? x : h;
        aggregate_kernel<<<(N_NODES * 64) / 256, 256, 0, stream>>>(hin, dis, offsets, edat, t);
        gemm_kernel<<<N_NODES / 64, 256, 0, stream>>>(
            t, conv_w + l * HDIM * HDIM, conv_b + l * HDIM,
            bn_gamma + l * HDIM, bn_beta + l * HDIM,
            bn_mean + l * HDIM, bn_var + l * HDIM, h, (l > 0) ? 1 : 0);
    }

    pool_kernel<<<NGRAPH, 256, 0, stream>>>(h, batch, repr);
    classify_kernel<<<NGRAPH, 64, 0, stream>>>(repr, cls_w1, cls_b1, cls_w2, cls_b2, out);
}

// Round 6
// 318.121 us; speedup vs baseline: 1.0649x; 1.0649x over previous
//
#include <hip/hip_runtime.h>
#include <hip/hip_fp16.h>
#include <math.h>

#define N_NODES 65536
#define N_EDGES 1048576
#define HDIM 64
#define NCLS 10
#define NGRAPH 256
#define NLAYER 3
#define BN_EPS 1e-5f

// ---------------- degree count ----------------

__global__ __launch_bounds__(256) void deg_count_kernel(const int* __restrict__ dst,
                                                        unsigned* __restrict__ cnt) {
    int e = blockIdx.x * 256 + threadIdx.x;
    if (e < N_EDGES) atomicAdd(&cnt[dst[e]], 1u);
}

// ---------------- CSR build: exclusive scan (+ dis fused) ----------------

__global__ __launch_bounds__(256) void scan1_kernel(const unsigned* __restrict__ cnt,
                                                    unsigned* __restrict__ offsets,
                                                    unsigned* __restrict__ bsum,
                                                    float* __restrict__ dis) {
    __shared__ unsigned lds[256];
    int t = threadIdx.x, b = blockIdx.x;
    unsigned v = cnt[b * 256 + t];
    dis[b * 256 + t] = rsqrtf((float)(v + 1u));
    lds[t] = v;
    __syncthreads();
#pragma unroll
    for (int off = 1; off < 256; off <<= 1) {
        unsigned add = (t >= off) ? lds[t - off] : 0u;
        __syncthreads();
        lds[t] += add;
        __syncthreads();
    }
    offsets[b * 256 + t] = lds[t] - v;  // exclusive within block
    if (t == 255) bsum[b] = lds[255];
}

__global__ __launch_bounds__(256) void scan2_kernel(unsigned* __restrict__ bsum,
                                                    unsigned* __restrict__ carry,
                                                    unsigned* __restrict__ offsets) {
    __shared__ unsigned lds[256];
    int t = threadIdx.x;
    unsigned v = bsum[t];
    lds[t] = v;
    __syncthreads();
#pragma unroll
    for (int off = 1; off < 256; off <<= 1) {
        unsigned add = (t >= off) ? lds[t - off] : 0u;
        __syncthreads();
        lds[t] += add;
        __syncthreads();
    }
    carry[t] = lds[t] - v;  // exclusive
    if (t == 255) offsets[N_NODES] = lds[255];  // total = E
}

__global__ __launch_bounds__(256) void scan3_kernel(unsigned* __restrict__ offsets,
                                                    const unsigned* __restrict__ carry) {
    int i = blockIdx.x * 256 + threadIdx.x;
    if (i < N_NODES) offsets[i] += carry[i >> 8];
}

// R4-style fill: atomic rank on zeroed cursor + read-only offsets gather
__global__ __launch_bounds__(256) void fill_kernel(const int* __restrict__ ei,
                                                   const float* __restrict__ dis,
                                                   const unsigned* __restrict__ offsets,
                                                   unsigned* __restrict__ cursor,
                                                   int2* __restrict__ edat) {
    int e = blockIdx.x * 256 + threadIdx.x;
    if (e < N_EDGES) {
        int s = ei[e];
        int d = ei[N_EDGES + e];
        unsigned r = atomicAdd(&cursor[d], 1u);
        unsigned pos = offsets[d] + r;
        float c = dis[s] * dis[d];
        edat[pos] = make_int2(s, __float_as_int(c));
    }
}

// ---------------- fp32 -> fp16 cast (for gather payload) ----------------

__global__ __launch_bounds__(256) void cast_kernel(const float* __restrict__ x,
                                                   __half* __restrict__ h16) {
    int i = blockIdx.x * 256 + threadIdx.x;  // float4 index, N*16 total
    float4 v = ((const float4*)x)[i];
    __half2 a = __floats2half2_rn(v.x, v.y);
    __half2 b = __floats2half2_rn(v.z, v.w);
    uint2 o;
    o.x = *(unsigned*)&a;
    o.y = *(unsigned*)&b;
    ((uint2*)h16)[i] = o;
}

// ---------------- pull aggregate: t[n] = dis[n]^2*h[n] + sum coef*h16[src] ----------------
// one wave per node; lanes = 4 edge-slots x 16 feature lanes (4 halves each).
// main loop: 16 edge gathers (8B each) in flight per wave.

__global__ __launch_bounds__(256) void aggregate_kernel(const __half* __restrict__ h16,
                                                        const float* __restrict__ hin32,
                                                        const float* __restrict__ dis,
                                                        const unsigned* __restrict__ offsets,
                                                        const int2* __restrict__ edat,
                                                        float* __restrict__ t) {
    int n = (blockIdx.x * 256 + threadIdx.x) >> 6;
    int lane = threadIdx.x & 63;
    int eslot = lane >> 4;      // 0..3
    int fq = lane & 15;         // 4-half feature chunk index
    int e0 = (int)offsets[n];
    int e1 = (int)offsets[n + 1];

    const uint2* hv = (const uint2*)h16;  // 8B = 4 halves per chunk, 16 chunks per row

    float4 acc = make_float4(0.f, 0.f, 0.f, 0.f);
    int e = e0 + eslot;
    // unrolled x4: 16 edges in flight across the wave
    for (; e + 12 < e1; e += 16) {
        int2 s0 = edat[e];
        int2 s1 = edat[e + 4];
        int2 s2 = edat[e + 8];
        int2 s3 = edat[e + 12];
        uint2 r0 = hv[((size_t)s0.x << 4) + fq];
        uint2 r1 = hv[((size_t)s1.x << 4) + fq];
        uint2 r2 = hv[((size_t)s2.x << 4) + fq];
        uint2 r3 = hv[((size_t)s3.x << 4) + fq];
        float c0 = __int_as_float(s0.y);
        float c1 = __int_as_float(s1.y);
        float c2 = __int_as_float(s2.y);
        float c3 = __int_as_float(s3.y);
        {
            float2 lo = __half22float2(*(__half2*)&r0.x);
            float2 hi = __half22float2(*(__half2*)&r0.y);
            acc.x += lo.x * c0; acc.y += lo.y * c0; acc.z += hi.x * c0; acc.w += hi.y * c0;
        }
        {
            float2 lo = __half22float2(*(__half2*)&r1.x);
            float2 hi = __half22float2(*(__half2*)&r1.y);
            acc.x += lo.x * c1; acc.y += lo.y * c1; acc.z += hi.x * c1; acc.w += hi.y * c1;
        }
        {
            float2 lo = __half22float2(*(__half2*)&r2.x);
            float2 hi = __half22float2(*(__half2*)&r2.y);
            acc.x += lo.x * c2; acc.y += lo.y * c2; acc.z += hi.x * c2; acc.w += hi.y * c2;
        }
        {
            float2 lo = __half22float2(*(__half2*)&r3.x);
            float2 hi = __half22float2(*(__half2*)&r3.y);
            acc.x += lo.x * c3; acc.y += lo.y * c3; acc.z += hi.x * c3; acc.w += hi.y * c3;
        }
    }
    for (; e < e1; e += 4) {
        int2 sa = edat[e];
        float ca = __int_as_float(sa.y);
        uint2 ra = hv[((size_t)sa.x << 4) + fq];
        float2 lo = __half22float2(*(__half2*)&ra.x);
        float2 hi = __half22float2(*(__half2*)&ra.y);
        acc.x += lo.x * ca; acc.y += lo.y * ca; acc.z += hi.x * ca; acc.w += hi.y * ca;
    }
    // reduce across edge slots (lanes l, l^16, l^32, l^48)
    acc.x += __shfl_xor(acc.x, 16); acc.y += __shfl_xor(acc.y, 16);
    acc.z += __shfl_xor(acc.z, 16); acc.w += __shfl_xor(acc.w, 16);
    acc.x += __shfl_xor(acc.x, 32); acc.y += __shfl_xor(acc.y, 32);
    acc.z += __shfl_xor(acc.z, 32); acc.w += __shfl_xor(acc.w, 32);
    if (eslot == 0) {
        float d = dis[n];
        float d2 = d * d;
        float4 sv = *(const float4*)&hin32[(size_t)n * HDIM + (fq << 2)];
        acc.x += sv.x * d2; acc.y += sv.y * d2;
        acc.z += sv.z * d2; acc.w += sv.w * d2;
        *(float4*)&t[(size_t)n * HDIM + (fq << 2)] = acc;
    }
}

// ---------------- GEMM t@W fused with bias+BN+ReLU+residual; writes h (f32) + h16 ----------------

__global__ __launch_bounds__(256) void gemm_kernel(const float* __restrict__ tin,
                                                   const float* __restrict__ W,
                                                   const float* __restrict__ bias,
                                                   const float* __restrict__ gamma,
                                                   const float* __restrict__ beta,
                                                   const float* __restrict__ mean,
                                                   const float* __restrict__ var,
                                                   float* __restrict__ h,
                                                   __half* __restrict__ h16,
                                                   int has_res) {
    __shared__ float hs[64][68];
    __shared__ float ws[64 * 64];
    int tid = threadIdx.x;
    int row0 = blockIdx.x * 64;

    {
        const float4* Wv = (const float4*)W;
        float4* wsv = (float4*)ws;
#pragma unroll
        for (int i = 0; i < 4; ++i) wsv[tid + i * 256] = Wv[tid + i * 256];
    }
    {
        const float4* Hv = (const float4*)(tin + (size_t)row0 * HDIM);
#pragma unroll
        for (int i = 0; i < 4; ++i) {
            int idx = tid + i * 256;
            int r = idx >> 4;
            int c = (idx & 15) << 2;
            *(float4*)&hs[r][c] = Hv[idx];
        }
    }
    __syncthreads();

    int tx = tid & 15, ty = tid >> 4;
    float acc[4][4] = {};
#pragma unroll
    for (int kq = 0; kq < 16; ++kq) {
        int k = kq * 4;
        float4 a[4], b[4];
#pragma unroll
        for (int i = 0; i < 4; ++i) a[i] = *(const float4*)&hs[ty * 4 + i][k];
#pragma unroll
        for (int kk = 0; kk < 4; ++kk) b[kk] = *(const float4*)&ws[(k + kk) * 64 + tx * 4];
#pragma unroll
        for (int kk = 0; kk < 4; ++kk) {
            float b0 = b[kk].x, b1 = b[kk].y, b2 = b[kk].z, b3 = b[kk].w;
#pragma unroll
            for (int i = 0; i < 4; ++i) {
                float av = (kk == 0) ? a[i].x : (kk == 1) ? a[i].y : (kk == 2) ? a[i].z : a[i].w;
                acc[i][0] += av * b0;
                acc[i][1] += av * b1;
                acc[i][2] += av * b2;
                acc[i][3] += av * b3;
            }
        }
    }

    float4 b4 = ((const float4*)bias)[tx];
    float4 g4 = ((const float4*)gamma)[tx];
    float4 be4 = ((const float4*)beta)[tx];
    float4 m4 = ((const float4*)mean)[tx];
    float4 va4 = ((const float4*)var)[tx];
    float sc0 = g4.x * rsqrtf(va4.x + BN_EPS);
    float sc1 = g4.y * rsqrtf(va4.y + BN_EPS);
    float sc2 = g4.z * rsqrtf(va4.z + BN_EPS);
    float sc3 = g4.w * rsqrtf(va4.w + BN_EPS);
    float sh0 = (b4.x - m4.x) * sc0 + be4.x;
    float sh1 = (b4.y - m4.y) * sc1 + be4.y;
    float sh2 = (b4.z - m4.z) * sc2 + be4.z;
    float sh3 = (b4.w - m4.w) * sc3 + be4.w;

#pragma unroll
    for (int i = 0; i < 4; ++i) {
        int row = row0 + ty * 4 + i;
        float o0 = fmaxf(acc[i][0] * sc0 + sh0, 0.0f);
        float o1 = fmaxf(acc[i][1] * sc1 + sh1, 0.0f);
        float o2 = fmaxf(acc[i][2] * sc2 + sh2, 0.0f);
        float o3 = fmaxf(acc[i][3] * sc3 + sh3, 0.0f);
        if (has_res) {
            float4 r = *(const float4*)&h[(size_t)row * HDIM + tx * 4];
            o0 += r.x; o1 += r.y; o2 += r.z; o3 += r.w;
        }
        *(float4*)&h[(size_t)row * HDIM + tx * 4] = make_float4(o0, o1, o2, o3);
        __half2 pa = __floats2half2_rn(o0, o1);
        __half2 pb = __floats2half2_rn(o2, o3);
        uint2 pk;
        pk.x = *(unsigned*)&pa;
        pk.y = *(unsigned*)&pb;
        *(uint2*)&h16[(size_t)row * HDIM + tx * 4] = pk;
    }
}

// ---------------- global mean pool over sorted batch ----------------

__device__ __forceinline__ int lower_bound_batch(const int* __restrict__ batch, int val) {
    int lo = 0, hi = N_NODES;
    while (lo < hi) {
        int mid = (lo + hi) >> 1;
        if (batch[mid] < val) lo = mid + 1; else hi = mid;
    }
    return lo;
}

__global__ __launch_bounds__(256) void pool_kernel(const float* __restrict__ h,
                                                   const int* __restrict__ batch,
                                                   float* __restrict__ repr) {
    int g = blockIdx.x;
    int start = lower_bound_batch(batch, g);
    int end = lower_bound_batch(batch, g + 1);
    int f = threadIdx.x & 63;
    int grp = threadIdx.x >> 6;
    float s0 = 0.f, s1 = 0.f, s2 = 0.f, s3 = 0.f;
    int n = start + grp;
    for (; n + 12 < end; n += 16) {
        s0 += h[(size_t)n * HDIM + f];
        s1 += h[(size_t)(n + 4) * HDIM + f];
        s2 += h[(size_t)(n + 8) * HDIM + f];
        s3 += h[(size_t)(n + 12) * HDIM + f];
    }
    for (; n < end; n += 4) s0 += h[(size_t)n * HDIM + f];
    float s = (s0 + s1) + (s2 + s3);
    __shared__ float red[4][64];
    red[grp][f] = s;
    __syncthreads();
    if (grp == 0) {
        float tot = red[0][f] + red[1][f] + red[2][f] + red[3][f];
        int cnt = end - start;
        repr[g * HDIM + f] = tot / (float)(cnt > 0 ? cnt : 1);
    }
}

// ---------------- classifier ----------------

__global__ __launch_bounds__(64) void classify_kernel(const float* __restrict__ repr,
                                                      const float* __restrict__ w1,
                                                      const float* __restrict__ b1,
                                                      const float* __restrict__ w2,
                                                      const float* __restrict__ b2,
                                                      float* __restrict__ out) {
    int g = blockIdx.x;
    int j = threadIdx.x;
    __shared__ float r[64], z[64], lg[NCLS];
    r[j] = repr[g * HDIM + j];
    __syncthreads();
    float acc = b1[j];
#pragma unroll 8
    for (int k = 0; k < HDIM; ++k) acc += r[k] * w1[k * HDIM + j];
    z[j] = fmaxf(acc, 0.0f);
    __syncthreads();
    if (j < NCLS) {
        float a2 = b2[j];
#pragma unroll 8
        for (int k = 0; k < HDIM; ++k) a2 += z[k] * w2[k * NCLS + j];
        lg[j] = a2;
    }
    __syncthreads();
    if (j < NCLS) {
        float m = -1e30f;
#pragma unroll
        for (int c = 0; c < NCLS; ++c) m = fmaxf(m, lg[c]);
        float s = 0.0f;
#pragma unroll
        for (int c = 0; c < NCLS; ++c) s += expf(lg[c] - m);
        out[g * NCLS + j] = lg[j] - m - logf(s);
    }
}

// ---------------- host side ----------------

extern "C" void kernel_launch(void* const* d_in, const int* in_sizes, int n_in,
                              void* d_out, int out_size, void* d_ws, size_t ws_size,
                              hipStream_t stream) {
    const float* x        = (const float*)d_in[0];
    const float* conv_w   = (const float*)d_in[1];
    const float* conv_b   = (const float*)d_in[2];
    const float* bn_gamma = (const float*)d_in[3];
    const float* bn_beta  = (const float*)d_in[4];
    const float* bn_mean  = (const float*)d_in[5];
    const float* bn_var   = (const float*)d_in[6];
    const float* cls_w1   = (const float*)d_in[7];
    const float* cls_b1   = (const float*)d_in[8];
    const float* cls_w2   = (const float*)d_in[9];
    const float* cls_b2   = (const float*)d_in[10];
    const int* edge_index = (const int*)d_in[11];
    const int* batch      = (const int*)d_in[12];
    float* out = (float*)d_out;

    char* ws = (char*)d_ws;
    unsigned* cursor  = (unsigned*)(ws);                  // 256 KiB
    float*    dis     = (float*)(ws + (256u << 10));      // 256 KiB
    unsigned* offsets = (unsigned*)(ws + (512u << 10));   // 256 KiB + 4
    unsigned* bsum    = (unsigned*)(ws + (832u << 10));   // 1 KiB
    unsigned* carry   = (unsigned*)(ws + (833u << 10));   // 1 KiB
    int2*     edat    = (int2*)(ws + (2u << 20));         // 8 MiB (src, coef packed)
    float*    t       = (float*)(ws + (10u << 20));       // 16 MiB
    float*    h       = (float*)(ws + (26u << 20));       // 16 MiB
    float*    repr    = (float*)(ws + (42u << 20));       // 64 KiB
    __half*   h16     = (__half*)(ws + (43u << 20));      // 8 MiB

    // ---- preprocessing (CSR by dst) ----
    hipMemsetAsync(cursor, 0, N_NODES * sizeof(unsigned), stream);
    deg_count_kernel<<<N_EDGES / 256, 256, 0, stream>>>(edge_index + N_EDGES, cursor);
    scan1_kernel<<<N_NODES / 256, 256, 0, stream>>>(cursor, offsets, bsum, dis);
    scan2_kernel<<<1, 256, 0, stream>>>(bsum, carry, offsets);
    scan3_kernel<<<N_NODES / 256, 256, 0, stream>>>(offsets, carry);
    hipMemsetAsync(cursor, 0, N_NODES * sizeof(unsigned), stream);
    fill_kernel<<<N_EDGES / 256, 256, 0, stream>>>(edge_index, dis, offsets, cursor, edat);
    cast_kernel<<<(N_NODES * 16) / 256, 256, 0, stream>>>(x, h16);

    // ---- layers ----
    for (int l = 0; l < NLAYER; ++l) {
        const float* hin32 = (l == 0) ? x : h;
        aggregate_kernel<<<(N_NODES * 64) / 256, 256, 0, stream>>>(h16, hin32, dis, offsets, edat, t);
        gemm_kernel<<<N_NODES / 64, 256, 0, stream>>>(
            t, conv_w + l * HDIM * HDIM, conv_b + l * HDIM,
            bn_gamma + l * HDIM, bn_beta + l * HDIM,
            bn_mean + l * HDIM, bn_var + l * HDIM, h, h16, (l > 0) ? 1 : 0);
    }

    pool_kernel<<<NGRAPH, 256, 0, stream>>>(h, batch, repr);
    classify_kernel<<<NGRAPH, 64, 0, stream>>>(repr, cls_w1, cls_b1, cls_w2, cls_b2, out);
}